// Round 3
// baseline (415.163 us; speedup 1.0000x reference)
//
#include <hip/hip_runtime.h>

// Problem constants (from reference): B=64, TOPK=2, E=16, C=1024, K=4096
#define BB    64
#define TOPK  2
#define EE    16
#define CC    1024
#define KK    4096

constexpr int RPB = 16;            // weight rows per block (4 per wave, 1 per 16-lane group)
constexpr int P   = 16;            // max (token,slot) pairs per chunk
constexpr int KS  = 8;             // K-split (partial sums via atomics)
constexpr int KH  = KK / KS;       // floats per K-slice (=512)
constexpr int NS  = KH / 64;       // 64-float steps per slice (=8)

typedef float v4f __attribute__((ext_vector_type(4)));

// ---------------------------------------------------------------------------
// Kernel 1: block 0 builds per-expert routing lists; other blocks initialize
//   out[b,c] = residual[b,c] + sum_s ew[b,s] * bias[idx[b,s], c]
// ---------------------------------------------------------------------------
__global__ __launch_bounds__(256) void route_init(
    const int* __restrict__ idx, const float* __restrict__ ew,
    const float* __restrict__ bias, const float* __restrict__ resid,
    float* __restrict__ out, int* __restrict__ cnt, int* __restrict__ lists)
{
    if (blockIdx.x == 0) {
        __shared__ int scnt[EE];
        if (threadIdx.x < EE) scnt[threadIdx.x] = 0;
        __syncthreads();
        if (threadIdx.x < BB * TOPK) {
            int e = idx[threadIdx.x];
            int pos = atomicAdd(&scnt[e], 1);
            lists[e * 128 + pos] = threadIdx.x;   // pair id = b*TOPK + slot
        }
        __syncthreads();
        if (threadIdx.x < EE) cnt[threadIdx.x] = scnt[threadIdx.x];
    } else {
        int i = (blockIdx.x - 1) * 256 + threadIdx.x;   // i in [0, B*C)
        int b = i >> 10;                                 // C = 1024
        int c = i & (CC - 1);
        float v = resid[i];
#pragma unroll
        for (int s = 0; s < TOPK; s++) {
            int e = idx[b * TOPK + s];
            v += ew[b * TOPK + s] * bias[e * CC + c];
        }
        out[i] = v;
    }
}

// ---------------------------------------------------------------------------
// Kernel 2: grid = E * (C/RPB) * KS = 8192 blocks, 256 threads.
//
// Round-2 lesson: moe_mlp2 fell under the 160us fill kernels, but the
// one-shot {load burst -> barrier drain -> LDS compute -> retire} phase
// machine still caps us ~3x above the 42us weight-stream floor (the fills
// themselves prove 6.7 TB/s is reachable).
//
// Round-3 restructure: NO LDS, NO barriers. act (2 MB) is L2-resident, so
// read it directly from global instead of staging. Lane remap: 16-lane
// group g owns weight row row0+g; lane j=lane&15 owns K elems j*4+s*64.
//   * weight loads: 8 nt dwordx4/lane, 4x256B segments/instr (coalesced)
//   * act loads:    same 16B address across the 4 groups -> HW merges to
//                   one 256B transaction/instr, served from L2 (~200cy)
//   * every wave fully independent: loads + FMAs pipeline continuously
//     under compiler vmcnt(N); no drain point anywhere in the kernel
//   * reduction: value-halving butterfly WITHIN 16-lane groups: 15 shfls
//     for all 64 (row,pair) sums; lane j<np fires exactly one atomic
// ---------------------------------------------------------------------------
__global__ __launch_bounds__(256, 4) void moe_mlp2(
    const float* __restrict__ act, const float* __restrict__ ew,
    const float* __restrict__ W, float* __restrict__ out,
    const int* __restrict__ cnt, const int* __restrict__ lists)
{
    const int bid = blockIdx.x;
    const int e   = bid >> 9;                 // 512 blocks per expert
    const int n   = cnt[e];
    if (n == 0) return;
    const int ct   = (bid >> 3) & 63;         // 64 row-tiles
    const int ks   = bid & (KS - 1);          // 8 K-slices
    const int lane = threadIdx.x & 63;
    const int wave = threadIdx.x >> 6;
    const int g16  = lane >> 4;               // group 0..3 (row within wave)
    const int j    = lane & 15;               // lane-in-group (K position)
    const int row  = ct * RPB + wave * 4 + g16;

    // --- this lane's weight slice: 8 nt dwordx4, issued back-to-back ---
    const v4f* __restrict__ Wr =
        (const v4f*)(W + (size_t)(e * CC + row) * KK + ks * KH) + j;
    v4f w[NS];
#pragma unroll
    for (int s = 0; s < NS; s++)
        w[s] = __builtin_nontemporal_load(Wr + s * 16);

    const float* __restrict__ actb = act + (size_t)ks * KH;

    for (int g = 0; g < n; g += P) {
        const int np = min(P, n - g);

        // per-lane routing info for the epilogue (issued early, used late)
        const int   prl = lists[e * 128 + g + (j < np ? j : 0)];
        const float wgt = ew[prl];

        float val[P];
#pragma unroll
        for (int p = 0; p < P; p++) val[p] = 0.f;

#pragma unroll
        for (int p = 0; p < P; p++) {
            if (p < np) {                          // wave-uniform guard
                const int pr = lists[e * 128 + g + p];   // uniform -> s_load
                const v4f* __restrict__ ap =
                    (const v4f*)(actb + (size_t)pr * KK) + j;
#pragma unroll
                for (int s = 0; s < NS; s++) {
                    const v4f a = ap[s * 16];
                    val[p] += w[s].x * a.x + w[s].y * a.y +
                              w[s].z * a.z + w[s].w * a.w;
                }
            }
        }

        // --- value-halving butterfly within each 16-lane group: 15 shfls.
        //     After step s, slot i (i % 2^(s+1)==0) holds the 2^(s+1)-lane
        //     partial of logical value (i | (j & (2^(s+1)-1))). After 4
        //     steps lane j's val[0] = full 16-lane sum for pair j.
        //     Dead pairs (>=np) contribute exact zeros, never garbage. ---
#pragma unroll
        for (int st = 0; st < 4; st++) {
            const int m = 1 << st;
            const bool hi = (lane & m) != 0;
#pragma unroll
            for (int i = 0; i < P; i += 2 * m) {
                float send = hi ? val[i] : val[i + m];
                float recv = __shfl_xor(send, m, 64);
                val[i] = (hi ? val[i + m] : val[i]) + recv;
            }
        }

        if (j < np)
            atomicAdd(out + (size_t)(prl >> 1) * CC + row, wgt * val[0]);
    }
}

extern "C" void kernel_launch(void* const* d_in, const int* in_sizes, int n_in,
                              void* d_out, int out_size, void* d_ws, size_t ws_size,
                              hipStream_t stream) {
    const float* act   = (const float*)d_in[0];   // [B, TOPK, K]
    const int*   idx   = (const int*)d_in[1];     // [B, TOPK]
    const float* ew    = (const float*)d_in[2];   // [B, TOPK]
    const float* W     = (const float*)d_in[3];   // [E, C, K]
    const float* bias  = (const float*)d_in[4];   // [E, C]
    const float* resid = (const float*)d_in[5];   // [B, C]
    float* out = (float*)d_out;

    int* cnt   = (int*)d_ws;          // 16 ints
    int* lists = (int*)d_ws + 64;     // 16 * 128 ints, 256B-aligned offset

    route_init<<<1 + (BB * CC) / 256, 256, 0, stream>>>(
        idx, ew, bias, resid, out, cnt, lists);
    moe_mlp2<<<EE * (CC / RPB) * KS, 256, 0, stream>>>(
        act, ew, W, out, cnt, lists);
}